// Round 1
// baseline (376.770 us; speedup 1.0000x reference)
//
#include <hip/hip_runtime.h>

// Problem constants (fixed by the reference)
#define B_     32
#define C_IN_  512
#define H_     56
#define W_     56
#define HW_    (H_ * W_)        // 3136
#define C_ENC_ 64
#define K_     256
#define BHW_   (B_ * HW_)       // 100352
#define PTS_ROW_ (3 + C_ENC_)   // 67

// ---------------------------------------------------------------------------
// k1: transpose conv_w [C_ENC, C_IN] -> Wt [C_IN, C_ENC]  (contiguous per-c
// columns so the conv kernels' uniform W reads merge into s_load_dwordx16)
// ---------------------------------------------------------------------------
__global__ __launch_bounds__(256) void k_transpose_w(
        const float* __restrict__ w, float* __restrict__ wt) {
    int i = blockIdx.x * 256 + threadIdx.x;          // 0 .. 32767
    if (i < C_ENC_ * C_IN_) {
        int o = i / C_IN_;
        int c = i % C_IN_;
        wt[c * C_ENC_ + o] = w[i];
    }
}

// ---------------------------------------------------------------------------
// k2: 1x1 conv + per-pixel squared L2 norm.
// One pixel per thread; 64 fp32 accumulators; inner loop over c:
//   - x load is coalesced across threads (consecutive pixels, same channel)
//   - Wt[c*64+o] is wave-uniform -> scalar loads (s_load), hot in L2
// fp32 sequential-c accumulation with fmaf: closest match to a naive numpy
// einsum reduction order (top-k ordering must track the reference's norms).
// ---------------------------------------------------------------------------
__global__ __launch_bounds__(256) void k_conv_norm(
        const float* __restrict__ F, const float* __restrict__ wt,
        const float* __restrict__ bias, float* __restrict__ norms) {
    int p = blockIdx.x * 256 + threadIdx.x;          // 392*256 == 100352 exact
    int b   = p / HW_;
    int pix = p - b * HW_;
    const float* f = F + (size_t)b * C_IN_ * HW_ + pix;

    float acc[C_ENC_];
    #pragma unroll
    for (int o = 0; o < C_ENC_; ++o) acc[o] = bias[o];

    for (int c = 0; c < C_IN_; ++c) {
        float x = f[(size_t)c * HW_];
        const float* wc = wt + c * C_ENC_;
        #pragma unroll
        for (int o = 0; o < C_ENC_; ++o) acc[o] = fmaf(x, wc[o], acc[o]);
    }

    float nrm = 0.0f;
    #pragma unroll
    for (int o = 0; o < C_ENC_; ++o) nrm = fmaf(acc[o], acc[o], nrm);
    norms[p] = nrm;
}

// ---------------------------------------------------------------------------
// k3: per-batch exact top-K via full bitonic sort of 4096-padded keys.
// key = (~float_bits(norm) << 32) | pixel_idx  -> ascending sort gives
// descending norm, ties broken by LOWER index first == jax.lax.top_k order.
// (norms are sums of squares -> nonnegative -> float bits are order-monotone)
// Also writes the full sw plane for this batch (d_out is poisoned; every
// element must be written every call).
// ---------------------------------------------------------------------------
#define SORT_N_ 4096
__global__ __launch_bounds__(512) void k_topk(
        const float* __restrict__ norms, unsigned int* __restrict__ topk,
        float* __restrict__ sw_out) {
    __shared__ unsigned long long keys[SORT_N_];     // 32 KB
    __shared__ unsigned char flags[HW_];             // 3136 B

    int b = blockIdx.x;
    const float* nb = norms + b * HW_;

    for (int i = threadIdx.x; i < SORT_N_; i += 512) {
        if (i < HW_) {
            unsigned int bits = __float_as_uint(nb[i]);
            keys[i] = ((unsigned long long)(~bits) << 32) | (unsigned int)i;
            flags[i] = 0;
        } else {
            keys[i] = ~0ULL;                         // pad sorts to the end
        }
    }
    __syncthreads();

    for (int k = 2; k <= SORT_N_; k <<= 1) {
        for (int j = k >> 1; j > 0; j >>= 1) {
            for (int i = threadIdx.x; i < SORT_N_; i += 512) {
                int ixj = i ^ j;
                if (ixj > i) {                       // each pair handled once
                    unsigned long long a = keys[i];
                    unsigned long long c = keys[ixj];
                    bool up = ((i & k) == 0);        // ascending segment
                    if ((a > c) == up) { keys[i] = c; keys[ixj] = a; }
                }
            }
            __syncthreads();
        }
    }

    if (threadIdx.x < K_) {
        unsigned long long kk = keys[threadIdx.x];
        unsigned int idx = (unsigned int)(kk & 0xFFFFFFFFu);
        topk[b * K_ + threadIdx.x] = idx;
        flags[idx] = 1;
    }
    __syncthreads();

    float* swb = sw_out + b * HW_;
    for (int i = threadIdx.x; i < HW_; i += 512)
        swb[i] = flags[i] ? 1.0f : 0.0f;
}

// ---------------------------------------------------------------------------
// k4: recompute conv feats for the 8192 selected pixels; write points rows
// [x, y, 0, feat0..feat63]. One wave per (b,k); thread o owns output chan o.
// Wt read is coalesced (64 lanes x 4B); x read is one broadcast transaction.
// ---------------------------------------------------------------------------
__global__ __launch_bounds__(64) void k_points(
        const float* __restrict__ F, const float* __restrict__ wt,
        const float* __restrict__ bias, const unsigned int* __restrict__ topk,
        float* __restrict__ points) {
    int bk = blockIdx.x;                             // 0 .. B*K-1
    int b = bk >> 8;                                 // K = 256
    int o = threadIdx.x;
    unsigned int p = topk[bk];

    const float* f = F + (size_t)b * C_IN_ * HW_ + p;
    float acc = bias[o];
    for (int c = 0; c < C_IN_; ++c)
        acc = fmaf(f[(size_t)c * HW_], wt[c * C_ENC_ + o], acc);

    float* row = points + (size_t)bk * PTS_ROW_;
    row[3 + o] = acc;
    if (o == 0) {
        row[0] = (float)(p % W_);                    // abs_ (x)
        row[1] = (float)(p / W_);                    // ord_ (y)
        row[2] = 0.0f;                               // depth
    }
}

// ---------------------------------------------------------------------------
// k5: x_out[b][o] = mean over K of points[b][k][3+o]
// ---------------------------------------------------------------------------
__global__ __launch_bounds__(64) void k_xout(
        const float* __restrict__ points, float* __restrict__ xout) {
    int b = blockIdx.x;
    int o = threadIdx.x;
    const float* pb = points + (size_t)b * K_ * PTS_ROW_ + 3 + o;
    float s = 0.0f;
    for (int k = 0; k < K_; ++k) s += pb[(size_t)k * PTS_ROW_];
    xout[b * C_ENC_ + o] = s * (1.0f / K_);
}

// ---------------------------------------------------------------------------
extern "C" void kernel_launch(void* const* d_in, const int* in_sizes, int n_in,
                              void* d_out, int out_size, void* d_ws, size_t ws_size,
                              hipStream_t stream) {
    const float* F    = (const float*)d_in[0];       // [B, C_IN, H, W]
    const float* w    = (const float*)d_in[1];       // [C_ENC, C_IN]
    const float* bias = (const float*)d_in[2];       // [C_ENC]

    float* out    = (float*)d_out;
    float* xout   = out;                             // [B, C_ENC]      (2048)
    float* sw     = out + B_ * C_ENC_;               // [B, 1, H, W]    (100352)
    float* points = sw + BHW_;                       // [B, K, 67]      (548864)

    // workspace: Wt (128 KB) | norms (392 KB) | topk idx (32 KB)  ~ 552 KB
    float* wt            = (float*)d_ws;
    float* norms         = wt + C_IN_ * C_ENC_;
    unsigned int* topk   = (unsigned int*)(norms + BHW_);

    k_transpose_w<<<128, 256, 0, stream>>>(w, wt);
    k_conv_norm  <<<BHW_ / 256, 256, 0, stream>>>(F, wt, bias, norms);
    k_topk       <<<B_, 512, 0, stream>>>(norms, topk, sw);
    k_points     <<<B_ * K_, 64, 0, stream>>>(F, wt, bias, topk, points);
    k_xout       <<<B_, 64, 0, stream>>>(points, xout);
}

// Round 2
// 290.332 us; speedup vs baseline: 1.2977x; 1.2977x over previous
//
#include <hip/hip_runtime.h>

// Problem constants (fixed by the reference)
#define B_     32
#define C_IN_  512
#define H_     56
#define W_     56
#define HW_    (H_ * W_)        // 3136
#define C_ENC_ 64
#define K_     256
#define BHW_   (B_ * HW_)       // 100352
#define PTS_ROW_ (3 + C_ENC_)   // 67

// ---------------------------------------------------------------------------
// k1: transpose conv_w [C_ENC, C_IN] -> Wt [C_IN, C_ENC]
// ---------------------------------------------------------------------------
__global__ __launch_bounds__(256) void k_transpose_w(
        const float* __restrict__ w, float* __restrict__ wt) {
    int i = blockIdx.x * 256 + threadIdx.x;          // 0 .. 32767
    if (i < C_ENC_ * C_IN_) {
        int o = i / C_IN_;
        int c = i % C_IN_;
        wt[c * C_ENC_ + o] = w[i];
    }
}

// ---------------------------------------------------------------------------
// k2 v2: 1x1 conv + per-pixel squared L2 norm.
// Block = 256 threads = 64 pixels x 4 channel-groups (16 out-chans each).
//   - 16 fp32 accumulators per thread -> stays in registers (v1's acc[64]
//     fell out of registers: VGPR_Count was 36, occupancy 16%, 297 us)
//   - 1568 blocks x 4 waves = 6272 waves -> ~77% occupancy (v1: 1568 waves)
//   - x loads coalesced (64 consecutive pixels; 3136%64==0 so b is uniform)
//   - wt reads wave-uniform (g via readfirstlane) -> scalar loads
// NUMERICS: each acc[o] is the identical sequential-c fmaf chain as the
// passing version, and the norm is summed sequentially over all 64 channels
// (via LDS) in the same order -> norms bit-identical -> same top-k.
// ---------------------------------------------------------------------------
__global__ __launch_bounds__(256) void k_conv_norm(
        const float* __restrict__ F, const float* __restrict__ wt,
        const float* __restrict__ bias, float* __restrict__ norms) {
    __shared__ float accs[64][65];                   // +1 pad: conflict-free

    int t = threadIdx.x;
    int pix_l = t & 63;
    int g = __builtin_amdgcn_readfirstlane(t >> 6);  // 0..3, wave-uniform
    int pb = blockIdx.x;                             // 0..1567
    int b = pb / 49;                                 // 3136/64 = 49
    int pix0 = (pb % 49) * 64;

    const float* f  = F + (size_t)b * (C_IN_ * HW_) + pix0 + pix_l;
    const float* wg = wt + g * 16;                   // wt layout [c][64]

    float acc[16];
    #pragma unroll
    for (int o = 0; o < 16; ++o) acc[o] = bias[g * 16 + o];

    #pragma unroll 4
    for (int c = 0; c < C_IN_; ++c) {
        float x = f[(size_t)c * HW_];
        #pragma unroll
        for (int o = 0; o < 16; ++o)
            acc[o] = fmaf(x, wg[c * C_ENC_ + o], acc[o]);
    }

    #pragma unroll
    for (int o = 0; o < 16; ++o) accs[pix_l][g * 16 + o] = acc[o];
    __syncthreads();

    if (t < 64) {
        float nrm = 0.0f;
        #pragma unroll
        for (int o = 0; o < C_ENC_; ++o)
            nrm = fmaf(accs[t][o], accs[t][o], nrm);
        norms[b * HW_ + pix0 + t] = nrm;
    }
}

// ---------------------------------------------------------------------------
// k3: per-batch exact top-K via full bitonic sort of 4096-padded keys.
// key = (~float_bits(norm) << 32) | pixel_idx -> ascending sort ==
// descending norm, ties -> lower index first == jax.lax.top_k order.
// Also writes the full sw plane (d_out is poisoned each timing run).
// ---------------------------------------------------------------------------
#define SORT_N_ 4096
__global__ __launch_bounds__(512) void k_topk(
        const float* __restrict__ norms, unsigned int* __restrict__ topk,
        float* __restrict__ sw_out) {
    __shared__ unsigned long long keys[SORT_N_];     // 32 KB
    __shared__ unsigned char flags[HW_];             // 3136 B

    int b = blockIdx.x;
    const float* nb = norms + b * HW_;

    for (int i = threadIdx.x; i < SORT_N_; i += 512) {
        if (i < HW_) {
            unsigned int bits = __float_as_uint(nb[i]);
            keys[i] = ((unsigned long long)(~bits) << 32) | (unsigned int)i;
            flags[i] = 0;
        } else {
            keys[i] = ~0ULL;                         // pad sorts to the end
        }
    }
    __syncthreads();

    for (int k = 2; k <= SORT_N_; k <<= 1) {
        for (int j = k >> 1; j > 0; j >>= 1) {
            for (int i = threadIdx.x; i < SORT_N_; i += 512) {
                int ixj = i ^ j;
                if (ixj > i) {
                    unsigned long long a = keys[i];
                    unsigned long long c = keys[ixj];
                    bool up = ((i & k) == 0);
                    if ((a > c) == up) { keys[i] = c; keys[ixj] = a; }
                }
            }
            __syncthreads();
        }
    }

    if (threadIdx.x < K_) {
        unsigned long long kk = keys[threadIdx.x];
        unsigned int idx = (unsigned int)(kk & 0xFFFFFFFFu);
        topk[b * K_ + threadIdx.x] = idx;
        flags[idx] = 1;
    }
    __syncthreads();

    float* swb = sw_out + b * HW_;
    for (int i = threadIdx.x; i < HW_; i += 512)
        swb[i] = flags[i] ? 1.0f : 0.0f;
}

// ---------------------------------------------------------------------------
// k4: recompute conv feats for the 8192 selected pixels; write points rows
// [x, y, 0, feat0..feat63]. One wave per (b,k); thread o owns out chan o.
// Same sequential-c fmaf chain -> feats bit-identical to the norm pass.
// ---------------------------------------------------------------------------
__global__ __launch_bounds__(64) void k_points(
        const float* __restrict__ F, const float* __restrict__ wt,
        const float* __restrict__ bias, const unsigned int* __restrict__ topk,
        float* __restrict__ points) {
    int bk = blockIdx.x;                             // 0 .. B*K-1
    int b = bk >> 8;                                 // K = 256
    int o = threadIdx.x;
    unsigned int p = topk[bk];

    const float* f = F + (size_t)b * C_IN_ * HW_ + p;
    float acc = bias[o];
    for (int c = 0; c < C_IN_; ++c)
        acc = fmaf(f[(size_t)c * HW_], wt[c * C_ENC_ + o], acc);

    float* row = points + (size_t)bk * PTS_ROW_;
    row[3 + o] = acc;
    if (o == 0) {
        row[0] = (float)(p % W_);                    // abs_ (x)
        row[1] = (float)(p / W_);                    // ord_ (y)
        row[2] = 0.0f;                               // depth
    }
}

// ---------------------------------------------------------------------------
// k5: x_out[b][o] = mean over K of points[b][k][3+o]
// ---------------------------------------------------------------------------
__global__ __launch_bounds__(64) void k_xout(
        const float* __restrict__ points, float* __restrict__ xout) {
    int b = blockIdx.x;
    int o = threadIdx.x;
    const float* pb = points + (size_t)b * K_ * PTS_ROW_ + 3 + o;
    float s = 0.0f;
    for (int k = 0; k < K_; ++k) s += pb[(size_t)k * PTS_ROW_];
    xout[b * C_ENC_ + o] = s * (1.0f / K_);
}

// ---------------------------------------------------------------------------
extern "C" void kernel_launch(void* const* d_in, const int* in_sizes, int n_in,
                              void* d_out, int out_size, void* d_ws, size_t ws_size,
                              hipStream_t stream) {
    const float* F    = (const float*)d_in[0];       // [B, C_IN, H, W]
    const float* w    = (const float*)d_in[1];       // [C_ENC, C_IN]
    const float* bias = (const float*)d_in[2];       // [C_ENC]

    float* out    = (float*)d_out;
    float* xout   = out;                             // [B, C_ENC]      (2048)
    float* sw     = out + B_ * C_ENC_;               // [B, 1, H, W]    (100352)
    float* points = sw + BHW_;                       // [B, K, 67]      (548864)

    // workspace: Wt (128 KB) | norms (392 KB) | topk idx (32 KB)
    float* wt            = (float*)d_ws;
    float* norms         = wt + C_IN_ * C_ENC_;
    unsigned int* topk   = (unsigned int*)(norms + BHW_);

    k_transpose_w<<<128, 256, 0, stream>>>(w, wt);
    k_conv_norm  <<<BHW_ / 64, 256, 0, stream>>>(F, wt, bias, norms);
    k_topk       <<<B_, 512, 0, stream>>>(norms, topk, sw);
    k_points     <<<B_ * K_, 64, 0, stream>>>(F, wt, bias, topk, points);
    k_xout       <<<B_, 64, 0, stream>>>(points, xout);
}

// Round 3
// 237.606 us; speedup vs baseline: 1.5857x; 1.2219x over previous
//
#include <hip/hip_runtime.h>

// Problem constants (fixed by the reference)
#define B_     32
#define C_IN_  512
#define H_     56
#define W_     56
#define HW_    (H_ * W_)        // 3136
#define C_ENC_ 64
#define K_     256
#define BHW_   (B_ * HW_)       // 100352
#define PTS_ROW_ (3 + C_ENC_)   // 67

// ---------------------------------------------------------------------------
// k1: transpose conv_w [C_ENC, C_IN] -> Wt [C_IN, C_ENC]
// ---------------------------------------------------------------------------
__global__ __launch_bounds__(256) void k_transpose_w(
        const float* __restrict__ w, float* __restrict__ wt) {
    int i = blockIdx.x * 256 + threadIdx.x;          // 0 .. 32767
    if (i < C_ENC_ * C_IN_) {
        int o = i / C_IN_;
        int c = i % C_IN_;
        wt[c * C_ENC_ + o] = w[i];
    }
}

// ---------------------------------------------------------------------------
// k2 v3: 1x1 conv + per-pixel squared L2 norm.
// Block = 256 threads = 64 pixels x 4 channel-groups (16 out-chans each).
// v2 was latency-bound (VALUBusy 41%, HBM 10%): unroll-4 gave only ~770cy of
// FMA cover per SIMD for ~900cy HBM-miss latency. v3: explicit 8-deep
// x-prefetch double-buffer -> 8 loads in flight, 256cy FMA per batch,
// ~6 waves/SIMD * 256 = 1500cy cover.
// NUMERICS: per-channel chain (bias, then c ascending fmaf) and the norm
// sum (o = 0..63 sequential fmaf) are bit-identical to the passing v2.
// ---------------------------------------------------------------------------
__global__ __launch_bounds__(256) void k_conv_norm(
        const float* __restrict__ F, const float* __restrict__ wt,
        const float* __restrict__ bias, float* __restrict__ norms) {
    __shared__ float accs[64][65];                   // +1 pad: conflict-free

    int t = threadIdx.x;
    int pix_l = t & 63;
    int g = __builtin_amdgcn_readfirstlane(t >> 6);  // 0..3, wave-uniform
    int pb = blockIdx.x;                             // 0..1567
    int b = pb / 49;                                 // 3136/64 = 49
    int pix0 = (pb % 49) * 64;

    const float* f  = F + (size_t)b * (C_IN_ * HW_) + pix0 + pix_l;
    const float* wg = wt + g * 16;                   // wt layout [c][64]

    float acc[16];
    #pragma unroll
    for (int o = 0; o < 16; ++o) acc[o] = bias[g * 16 + o];

    float x[8];
    #pragma unroll
    for (int u = 0; u < 8; ++u) x[u] = f[(size_t)u * HW_];

    for (int c0 = 0; c0 < C_IN_; c0 += 8) {
        // prefetch next batch (last iter: reload c=0..7, discarded)
        int cn = (c0 + 8 < C_IN_) ? (c0 + 8) : 0;
        float xn[8];
        #pragma unroll
        for (int u = 0; u < 8; ++u) xn[u] = f[(size_t)(cn + u) * HW_];

        #pragma unroll
        for (int u = 0; u < 8; ++u) {
            #pragma unroll
            for (int o = 0; o < 16; ++o)
                acc[o] = fmaf(x[u], wg[(c0 + u) * C_ENC_ + o], acc[o]);
        }
        #pragma unroll
        for (int u = 0; u < 8; ++u) x[u] = xn[u];
    }

    #pragma unroll
    for (int o = 0; o < 16; ++o) accs[pix_l][g * 16 + o] = acc[o];
    __syncthreads();

    if (t < 64) {
        float nrm = 0.0f;
        #pragma unroll
        for (int o = 0; o < C_ENC_; ++o)
            nrm = fmaf(accs[t][o], accs[t][o], nrm);
        norms[b * HW_ + pix0 + t] = nrm;
    }
}

// ---------------------------------------------------------------------------
// k3 v2: per-batch exact top-K.
//  1) 4-round radix select (8 bits/round) on norm float bits (nonneg ->
//     order-monotone) finds T = exact 256th-largest key. Histogram in LDS,
//     suffix-scan done by wave 0 via shuffles (no block-wide scan barriers).
//  2) compact all keys >= T (count >= 256; == 256 unless exact ties).
//  3) one 512-element bitonic sort of (~key<<32 | idx): ascending ==
//     (desc norm, asc idx) == jax.lax.top_k order incl. tie-break.
// v1 sorted all 4096 padded elems: 78 passes x 8 elems/thread ~= 80us.
// ---------------------------------------------------------------------------
__global__ __launch_bounds__(512) void k_topk(
        const float* __restrict__ norms, unsigned int* __restrict__ topk,
        float* __restrict__ sw_out) {
    __shared__ unsigned int keys[HW_];               // 12.25 KB
    __shared__ unsigned int hist[256];
    __shared__ unsigned long long sortbuf[512];      // 4 KB
    __shared__ unsigned int s_prefix, s_need, s_cnt;
    __shared__ unsigned char flags[HW_];

    int b = blockIdx.x;
    int t = threadIdx.x;
    const float* nb = norms + b * HW_;

    for (int i = t; i < HW_; i += 512) {
        keys[i] = __float_as_uint(nb[i]);
        flags[i] = 0;
    }
    if (t == 0) { s_prefix = 0u; s_need = K_; s_cnt = 0u; }
    for (int i = t; i < 512; i += 512) sortbuf[i] = ~0ULL;

    // ---- radix select: after round r, s_prefix = top 8(r+1) bits of T ----
    for (int r = 0; r < 4; ++r) {
        if (t < 256) hist[t] = 0u;
        __syncthreads();                             // hist zeroed; prefix visible
        unsigned int pfx = s_prefix;
        int shift = 24 - 8 * r;
        for (int i = t; i < HW_; i += 512) {
            unsigned int k = keys[i];
            bool ok = (r == 0) || ((k >> (32 - 8 * r)) == pfx);
            if (ok) atomicAdd(&hist[(k >> shift) & 0xFFu], 1u);
        }
        __syncthreads();
        if (t < 64) {                                // wave 0: suffix-scan 256 bins
            unsigned int h0 = hist[4 * t + 0];
            unsigned int h1 = hist[4 * t + 1];
            unsigned int h2 = hist[4 * t + 2];
            unsigned int h3 = hist[4 * t + 3];
            unsigned int tot = h0 + h1 + h2 + h3;
            unsigned int suf = tot;                  // suffix over lanes >= t
            #pragma unroll
            for (int off = 1; off < 64; off <<= 1) {
                unsigned int v = __shfl_down(suf, off);
                suf += (t + off < 64) ? v : 0u;
            }
            // G[v] = #cands with byte >= v ; G for this lane's 4 bins:
            unsigned int g0 = suf;                   // bin 4t
            unsigned int g1 = suf - h0;              // bin 4t+1
            unsigned int g2 = g1 - h1;               // bin 4t+2
            unsigned int g3 = g2 - h2;               // bin 4t+3
            unsigned int g4 = g3 - h3;               // == G[4t+4] (0 for t=63)
            unsigned int need = s_need;
            // exactly one bin v satisfies G[v] >= need > G[v+1]
            if (g0 >= need && g1 < need) { s_prefix = (pfx << 8) | (4u*t+0u); s_need = need - g1; }
            if (g1 >= need && g2 < need) { s_prefix = (pfx << 8) | (4u*t+1u); s_need = need - g2; }
            if (g2 >= need && g3 < need) { s_prefix = (pfx << 8) | (4u*t+2u); s_need = need - g3; }
            if (g3 >= need && g4 < need) { s_prefix = (pfx << 8) | (4u*t+3u); s_need = need - g4; }
        }
        __syncthreads();
    }
    unsigned int T = s_prefix;                       // exact 256th-largest key

    // ---- compact keys >= T (includes ties; >=256 items, ~256 typical) ----
    for (int i = t; i < HW_; i += 512) {
        unsigned int k = keys[i];
        if (k >= T) {
            unsigned int pos = atomicAdd(&s_cnt, 1u);
            if (pos < 512)
                sortbuf[pos] = ((unsigned long long)(~k) << 32) | (unsigned int)i;
        }
    }
    __syncthreads();

    // ---- bitonic sort 512 (asc) -> first 256 = top-k in reference order ----
    for (int kk = 2; kk <= 512; kk <<= 1) {
        for (int j = kk >> 1; j > 0; j >>= 1) {
            int ixj = t ^ j;
            if (ixj > t) {
                unsigned long long a = sortbuf[t], c = sortbuf[ixj];
                bool up = ((t & kk) == 0);
                if ((a > c) == up) { sortbuf[t] = c; sortbuf[ixj] = a; }
            }
            __syncthreads();
        }
    }

    if (t < K_) {
        unsigned long long e = sortbuf[t];
        unsigned int idx = (unsigned int)(e & 0xFFFFFFFFu);
        topk[b * K_ + t] = idx;
        flags[idx] = 1;
    }
    __syncthreads();

    float* swb = sw_out + b * HW_;
    for (int i = t; i < HW_; i += 512)
        swb[i] = flags[i] ? 1.0f : 0.0f;
}

// ---------------------------------------------------------------------------
// k4: recompute conv feats for the 8192 selected pixels; write points rows
// [x, y, 0, feat0..feat63]. One wave per (b,k); thread o owns out chan o.
// unroll 8 -> 8 broadcast f-loads in flight. Same sequential-c fmaf chain.
// ---------------------------------------------------------------------------
__global__ __launch_bounds__(64) void k_points(
        const float* __restrict__ F, const float* __restrict__ wt,
        const float* __restrict__ bias, const unsigned int* __restrict__ topk,
        float* __restrict__ points) {
    int bk = blockIdx.x;                             // 0 .. B*K-1
    int b = bk >> 8;                                 // K = 256
    int o = threadIdx.x;
    unsigned int p = topk[bk];

    const float* f = F + (size_t)b * C_IN_ * HW_ + p;
    float acc = bias[o];
    #pragma unroll 8
    for (int c = 0; c < C_IN_; ++c)
        acc = fmaf(f[(size_t)c * HW_], wt[c * C_ENC_ + o], acc);

    float* row = points + (size_t)bk * PTS_ROW_;
    row[3 + o] = acc;
    if (o == 0) {
        row[0] = (float)(p % W_);                    // abs_ (x)
        row[1] = (float)(p / W_);                    // ord_ (y)
        row[2] = 0.0f;                               // depth
    }
}

// ---------------------------------------------------------------------------
// k5: x_out[b][o] = mean over K of points[b][k][3+o]
// ---------------------------------------------------------------------------
__global__ __launch_bounds__(64) void k_xout(
        const float* __restrict__ points, float* __restrict__ xout) {
    int b = blockIdx.x;
    int o = threadIdx.x;
    const float* pb = points + (size_t)b * K_ * PTS_ROW_ + 3 + o;
    float s = 0.0f;
    #pragma unroll 8
    for (int k = 0; k < K_; ++k) s += pb[(size_t)k * PTS_ROW_];
    xout[b * C_ENC_ + o] = s * (1.0f / K_);
}

// ---------------------------------------------------------------------------
extern "C" void kernel_launch(void* const* d_in, const int* in_sizes, int n_in,
                              void* d_out, int out_size, void* d_ws, size_t ws_size,
                              hipStream_t stream) {
    const float* F    = (const float*)d_in[0];       // [B, C_IN, H, W]
    const float* w    = (const float*)d_in[1];       // [C_ENC, C_IN]
    const float* bias = (const float*)d_in[2];       // [C_ENC]

    float* out    = (float*)d_out;
    float* xout   = out;                             // [B, C_ENC]      (2048)
    float* sw     = out + B_ * C_ENC_;               // [B, 1, H, W]    (100352)
    float* points = sw + BHW_;                       // [B, K, 67]      (548864)

    // workspace: Wt (128 KB) | norms (392 KB) | topk idx (32 KB)
    float* wt            = (float*)d_ws;
    float* norms         = wt + C_IN_ * C_ENC_;
    unsigned int* topk   = (unsigned int*)(norms + BHW_);

    k_transpose_w<<<128, 256, 0, stream>>>(w, wt);
    k_conv_norm  <<<BHW_ / 64, 256, 0, stream>>>(F, wt, bias, norms);
    k_topk       <<<B_, 512, 0, stream>>>(norms, topk, sw);
    k_points     <<<B_ * K_, 64, 0, stream>>>(F, wt, bias, topk, points);
    k_xout       <<<B_, 64, 0, stream>>>(points, xout);
}

// Round 4
// 178.791 us; speedup vs baseline: 2.1073x; 1.3290x over previous
//
#include <hip/hip_runtime.h>

// Problem constants (fixed by the reference)
#define B_     32
#define C_IN_  512
#define H_     56
#define W_     56
#define HW_    (H_ * W_)        // 3136
#define C_ENC_ 64
#define K_     256
#define BHW_   (B_ * HW_)       // 100352
#define PTS_ROW_ (3 + C_ENC_)   // 67

// ---------------------------------------------------------------------------
// k1: transpose conv_w [C_ENC, C_IN] -> Wt [C_IN, C_ENC]
// ---------------------------------------------------------------------------
__global__ __launch_bounds__(256) void k_transpose_w(
        const float* __restrict__ w, float* __restrict__ wt) {
    int i = blockIdx.x * 256 + threadIdx.x;          // 0 .. 32767
    if (i < C_ENC_ * C_IN_) {
        int o = i / C_IN_;
        int c = i % C_IN_;
        wt[c * C_ENC_ + o] = w[i];
    }
}

// ---------------------------------------------------------------------------
// k2 v4: 1x1 conv + norm + feats store.
// Block = 256 threads = 64 pixels x 4 chan-groups (16 out-chans/thread).
//  - W unroll stays at 4 c's (64 scalar dwords -> fits SGPR budget; v3's
//    unroll-8 needed 128 W-SGPRs and likely demoted W to vector loads)
//  - x prefetch depth 8 via two static half-bodies (no runtime ring index)
//  - __launch_bounds__(256,8): force <=64 VGPR -> 8 waves/SIMD (est ~46)
//  - NEW: stores feats to ws in [b][o][pix] layout (coalesced dword stores)
//    so k_points/k_xout become trivial gathers of bit-identical values.
// NUMERICS: per-channel chain (bias, c-ascending fmaf) and the norm sum
// (accs via LDS, o=0..63 sequential fmaf) bit-identical to passing rounds.
// ---------------------------------------------------------------------------
__global__ __launch_bounds__(256, 8) void k_conv_norm(
        const float* __restrict__ F, const float* __restrict__ wt,
        const float* __restrict__ bias, float* __restrict__ norms,
        float* __restrict__ feats) {
    __shared__ float accs[64][65];                   // +1 pad: conflict-free

    int t = threadIdx.x;
    int pix_l = t & 63;
    int g = __builtin_amdgcn_readfirstlane(t >> 6);  // 0..3, wave-uniform
    int pb = blockIdx.x;                             // 0..1567
    int b = pb / 49;                                 // 3136/64 = 49
    int pix0 = (pb % 49) * 64;

    const float* f  = F + (size_t)b * (C_IN_ * HW_) + pix0 + pix_l;
    const float* wg = wt + g * 16;                   // wt layout [c][64]

    float acc[16];
    #pragma unroll
    for (int o = 0; o < 16; ++o) acc[o] = bias[g * 16 + o];

    float x[8];
    #pragma unroll
    for (int u = 0; u < 8; ++u) x[u] = f[(size_t)u * HW_];

    for (int c0 = 0; c0 < C_IN_; c0 += 8) {
        float xn[4];
        // ---- half A: prefetch c0+8..c0+11, FMA c0..c0+3 (W: 64 sgprs) ----
        int cA = (c0 + 8) & 511;                     // wraps harmlessly at end
        #pragma unroll
        for (int u = 0; u < 4; ++u) xn[u] = f[(size_t)(cA + u) * HW_];
        #pragma unroll
        for (int u = 0; u < 4; ++u)
            #pragma unroll
            for (int o = 0; o < 16; ++o)
                acc[o] = fmaf(x[u], wg[(c0 + u) * C_ENC_ + o], acc[o]);
        #pragma unroll
        for (int u = 0; u < 4; ++u) x[u] = xn[u];
        // ---- half B: prefetch c0+12..c0+15, FMA c0+4..c0+7 ----
        int cB = (c0 + 12) & 511;
        #pragma unroll
        for (int u = 0; u < 4; ++u) xn[u] = f[(size_t)(cB + u) * HW_];
        #pragma unroll
        for (int u = 0; u < 4; ++u)
            #pragma unroll
            for (int o = 0; o < 16; ++o)
                acc[o] = fmaf(x[4 + u], wg[(c0 + 4 + u) * C_ENC_ + o], acc[o]);
        #pragma unroll
        for (int u = 0; u < 4; ++u) x[4 + u] = xn[u];
    }

    // feats store: [b][o][pix] -> lanes contiguous, 16 coalesced dword stores
    #pragma unroll
    for (int o = 0; o < 16; ++o)
        feats[(size_t)(b * C_ENC_ + g * 16 + o) * HW_ + pix0 + pix_l] = acc[o];

    #pragma unroll
    for (int o = 0; o < 16; ++o) accs[pix_l][g * 16 + o] = acc[o];
    __syncthreads();

    if (t < 64) {
        float nrm = 0.0f;
        #pragma unroll
        for (int o = 0; o < C_ENC_; ++o)
            nrm = fmaf(accs[t][o], accs[t][o], nrm);
        norms[b * HW_ + pix0 + t] = nrm;
    }
}

// ---------------------------------------------------------------------------
// k3 v2 (unchanged, passed R3): radix-select exact 256th-largest key, compact
// >= T, bitonic-sort 512 -> exact jax.lax.top_k order (desc norm, asc idx).
// Also writes the full sw plane.
// ---------------------------------------------------------------------------
__global__ __launch_bounds__(512) void k_topk(
        const float* __restrict__ norms, unsigned int* __restrict__ topk,
        float* __restrict__ sw_out) {
    __shared__ unsigned int keys[HW_];               // 12.25 KB
    __shared__ unsigned int hist[256];
    __shared__ unsigned long long sortbuf[512];      // 4 KB
    __shared__ unsigned int s_prefix, s_need, s_cnt;
    __shared__ unsigned char flags[HW_];

    int b = blockIdx.x;
    int t = threadIdx.x;
    const float* nb = norms + b * HW_;

    for (int i = t; i < HW_; i += 512) {
        keys[i] = __float_as_uint(nb[i]);
        flags[i] = 0;
    }
    if (t == 0) { s_prefix = 0u; s_need = K_; s_cnt = 0u; }
    for (int i = t; i < 512; i += 512) sortbuf[i] = ~0ULL;

    for (int r = 0; r < 4; ++r) {
        if (t < 256) hist[t] = 0u;
        __syncthreads();
        unsigned int pfx = s_prefix;
        int shift = 24 - 8 * r;
        for (int i = t; i < HW_; i += 512) {
            unsigned int k = keys[i];
            bool ok = (r == 0) || ((k >> (32 - 8 * r)) == pfx);
            if (ok) atomicAdd(&hist[(k >> shift) & 0xFFu], 1u);
        }
        __syncthreads();
        if (t < 64) {                                // wave 0: suffix-scan
            unsigned int h0 = hist[4 * t + 0];
            unsigned int h1 = hist[4 * t + 1];
            unsigned int h2 = hist[4 * t + 2];
            unsigned int h3 = hist[4 * t + 3];
            unsigned int tot = h0 + h1 + h2 + h3;
            unsigned int suf = tot;
            #pragma unroll
            for (int off = 1; off < 64; off <<= 1) {
                unsigned int v = __shfl_down(suf, off);
                suf += (t + off < 64) ? v : 0u;
            }
            unsigned int g0 = suf;
            unsigned int g1 = suf - h0;
            unsigned int g2 = g1 - h1;
            unsigned int g3 = g2 - h2;
            unsigned int g4 = g3 - h3;
            unsigned int need = s_need;
            if (g0 >= need && g1 < need) { s_prefix = (pfx << 8) | (4u*t+0u); s_need = need - g1; }
            if (g1 >= need && g2 < need) { s_prefix = (pfx << 8) | (4u*t+1u); s_need = need - g2; }
            if (g2 >= need && g3 < need) { s_prefix = (pfx << 8) | (4u*t+2u); s_need = need - g3; }
            if (g3 >= need && g4 < need) { s_prefix = (pfx << 8) | (4u*t+3u); s_need = need - g4; }
        }
        __syncthreads();
    }
    unsigned int T = s_prefix;

    for (int i = t; i < HW_; i += 512) {
        unsigned int k = keys[i];
        if (k >= T) {
            unsigned int pos = atomicAdd(&s_cnt, 1u);
            if (pos < 512)
                sortbuf[pos] = ((unsigned long long)(~k) << 32) | (unsigned int)i;
        }
    }
    __syncthreads();

    for (int kk = 2; kk <= 512; kk <<= 1) {
        for (int j = kk >> 1; j > 0; j >>= 1) {
            int ixj = t ^ j;
            if (ixj > t) {
                unsigned long long a = sortbuf[t], c = sortbuf[ixj];
                bool up = ((t & kk) == 0);
                if ((a > c) == up) { sortbuf[t] = c; sortbuf[ixj] = a; }
            }
            __syncthreads();
        }
    }

    if (t < K_) {
        unsigned long long e = sortbuf[t];
        unsigned int idx = (unsigned int)(e & 0xFFFFFFFFu);
        topk[b * K_ + t] = idx;
        flags[idx] = 1;
    }
    __syncthreads();

    float* swb = sw_out + b * HW_;
    for (int i = t; i < HW_; i += 512)
        swb[i] = flags[i] ? 1.0f : 0.0f;
}

// ---------------------------------------------------------------------------
// k4 v2: pure gather. One wave per (b,k): lane o reads feats[b][o][p]
// (one scattered-line load instr), writes the 67-float points row.
// Values bit-identical to conv pass (same producer).
// ---------------------------------------------------------------------------
__global__ __launch_bounds__(64) void k_points(
        const float* __restrict__ feats, const unsigned int* __restrict__ topk,
        float* __restrict__ points) {
    int bk = blockIdx.x;                             // 0 .. B*K-1
    int b = bk >> 8;                                 // K = 256
    int o = threadIdx.x;
    unsigned int p = topk[bk];

    float v = feats[(size_t)(b * C_ENC_ + o) * HW_ + p];
    float* row = points + (size_t)bk * PTS_ROW_;
    row[3 + o] = v;
    if (o == 0) {
        row[0] = (float)(p % W_);                    // abs_ (x)
        row[1] = (float)(p / W_);                    // ord_ (y)
        row[2] = 0.0f;                               // depth
    }
}

// ---------------------------------------------------------------------------
// k5 v2: x_out[b][o] = mean over K of feats[b][o][idx_k], k ascending
// (matches reference mean order). Indices staged in LDS (broadcast reads).
// ---------------------------------------------------------------------------
__global__ __launch_bounds__(64) void k_xout(
        const float* __restrict__ feats, const unsigned int* __restrict__ topk,
        float* __restrict__ xout) {
    __shared__ unsigned int sidx[K_];
    int b = blockIdx.x;
    int t = threadIdx.x;
    for (int r = t; r < K_; r += 64) sidx[r] = topk[b * K_ + r];
    __syncthreads();

    const float* fb = feats + (size_t)(b * C_ENC_ + t) * HW_;
    float s = 0.0f;
    #pragma unroll 8
    for (int k = 0; k < K_; ++k) s += fb[sidx[k]];
    xout[b * C_ENC_ + t] = s * (1.0f / K_);
}

// ---------------------------------------------------------------------------
extern "C" void kernel_launch(void* const* d_in, const int* in_sizes, int n_in,
                              void* d_out, int out_size, void* d_ws, size_t ws_size,
                              hipStream_t stream) {
    const float* F    = (const float*)d_in[0];       // [B, C_IN, H, W]
    const float* w    = (const float*)d_in[1];       // [C_ENC, C_IN]
    const float* bias = (const float*)d_in[2];       // [C_ENC]

    float* out    = (float*)d_out;
    float* xout   = out;                             // [B, C_ENC]      (2048)
    float* sw     = out + B_ * C_ENC_;               // [B, 1, H, W]    (100352)
    float* points = sw + BHW_;                       // [B, K, 67]      (548864)

    // workspace: feats [B,64,HW] 25.7MB | Wt 128KB | norms 392KB | topk 32KB
    float* feats         = (float*)d_ws;
    float* wt            = feats + (size_t)B_ * C_ENC_ * HW_;
    float* norms         = wt + C_IN_ * C_ENC_;
    unsigned int* topk   = (unsigned int*)(norms + BHW_);

    k_transpose_w<<<128, 256, 0, stream>>>(w, wt);
    k_conv_norm  <<<BHW_ / 64, 256, 0, stream>>>(F, wt, bias, norms, feats);
    k_topk       <<<B_, 512, 0, stream>>>(norms, topk, sw);
    k_points     <<<B_ * K_, 64, 0, stream>>>(feats, topk, points);
    k_xout       <<<B_, 64, 0, stream>>>(feats, topk, xout);
}

// Round 5
// 163.071 us; speedup vs baseline: 2.3105x; 1.0964x over previous
//
#include <hip/hip_runtime.h>

// Problem constants (fixed by the reference)
#define B_     32
#define C_IN_  512
#define H_     56
#define W_     56
#define HW_    (H_ * W_)        // 3136
#define C_ENC_ 64
#define K_     256
#define BHW_   (B_ * HW_)       // 100352
#define PTS_ROW_ (3 + C_ENC_)   // 67

#define CHUNK_ 16               // channels staged per step
#define NSTEP_ (C_IN_ / CHUNK_) // 32
#define NBUF_  3                // LA=1 lookahead needs NBUF >= LA+2

// ---------------------------------------------------------------------------
// k1: transpose conv_w [C_ENC, C_IN] -> Wt [C_IN, C_ENC]
// ---------------------------------------------------------------------------
__global__ __launch_bounds__(256) void k_transpose_w(
        const float* __restrict__ w, float* __restrict__ wt) {
    int i = blockIdx.x * 256 + threadIdx.x;          // 0 .. 32767
    if (i < C_ENC_ * C_IN_) {
        int o = i / C_IN_;
        int c = i % C_IN_;
        wt[c * C_ENC_ + o] = w[i];
    }
}

// async global->LDS, 4 bytes per lane; LDS dest = wave-uniform base + lane*4,
// global src is per-lane (guide §5). One call = one channel row of 64 pixels.
__device__ __forceinline__ void gload_lds4(const float* g, float* l) {
    __builtin_amdgcn_global_load_lds(
        (const __attribute__((address_space(1))) void*)g,
        (__attribute__((address_space(3))) void*)l, 4, 0, 0);
}

// ---------------------------------------------------------------------------
// k2 v5: 1x1 conv + norm + feats store — LDS-staged 3-buffer pipeline.
// v4 was latency-bound (VALU 52%, VGPR squeezed to 28 by launch_bounds(,8);
// every wave redundantly issued all 512 x-loads). v5:
//  - each wave stages only ITS 4 channels per 16-ch step via global_load_lds
//    (4x fewer VMEM issues, no VGPR round-trip)
//  - 3 LDS buffers, lookahead 1, counted s_waitcnt vmcnt(4): next-step loads
//    stay in flight across the barrier (T3/T4 pattern; NBUF=3 proven safe:
//    stage(s+1) overwrites slot last read by compute(s-2), which all waves
//    finished before barrier(s-1), and stage(s+1) executes after it)
//  - compute: 16 x ds_read_b32 (2 lanes/bank = free) + 256 FMA per step
// NUMERICS: per-(pixel,o) chain (bias, c-ascending fmaf) bit-identical to
// all passing rounds -> feats bit-identical. Norm now sums 4 group partials
// (each o-ascending): ~1e-7 rel reorder noise, far under the top-k boundary
// gap already proven by 4 passing rounds.
// ---------------------------------------------------------------------------
__global__ __launch_bounds__(256) void k_conv_norm(
        const float* __restrict__ F, const float* __restrict__ wt,
        const float* __restrict__ bias, float* __restrict__ norms,
        float* __restrict__ feats) {
    __shared__ float xbuf[NBUF_][CHUNK_][64];        // 12 KB
    __shared__ float nrmp[64][4];                    // 1 KB

    int t = threadIdx.x;
    int pix_l = t & 63;
    int g = __builtin_amdgcn_readfirstlane(t >> 6);  // 0..3, wave-uniform
    int pb = blockIdx.x;                             // 0..1567
    int b = pb / 49;                                 // 3136/64 = 49
    int pix0 = (pb % 49) * 64;

    const float* f  = F + (size_t)b * (C_IN_ * HW_) + pix0 + pix_l;
    const float* wg = wt + g * 16;                   // wt layout [c][64]

    float acc[16];
    #pragma unroll
    for (int o = 0; o < 16; ++o) acc[o] = bias[g * 16 + o];

    // prologue: stage step 0 (this wave's 4 channels)
    #pragma unroll
    for (int u = 0; u < 4; ++u)
        gload_lds4(f + (size_t)(g * 4 + u) * HW_, &xbuf[0][g * 4 + u][0]);

    for (int s = 0; s < NSTEP_; ++s) {
        if (s + 1 < NSTEP_) {
            int cn = (s + 1) * CHUNK_ + g * 4;
            int slot = (s + 1) % NBUF_;
            #pragma unroll
            for (int u = 0; u < 4; ++u)
                gload_lds4(f + (size_t)(cn + u) * HW_, &xbuf[slot][g * 4 + u][0]);
            // outstanding: stage(s) 4 + stage(s+1) 4; wait stage(s) landed
            asm volatile("s_waitcnt vmcnt(4)" ::: "memory");
        } else {
            asm volatile("s_waitcnt vmcnt(0)" ::: "memory");
        }
        __builtin_amdgcn_sched_barrier(0);
        __syncthreads();                             // all waves' stage(s) done

        int slot = s % NBUF_;
        int cb = s * CHUNK_;
        #pragma unroll
        for (int cl = 0; cl < CHUNK_; ++cl) {
            float x = xbuf[slot][cl][pix_l];
            #pragma unroll
            for (int o = 0; o < 16; ++o)
                acc[o] = fmaf(x, wg[(cb + cl) * C_ENC_ + o], acc[o]);
        }
    }

    // feats store: [b][o][pix] -> 16 coalesced dword stores
    #pragma unroll
    for (int o = 0; o < 16; ++o)
        feats[(size_t)(b * C_ENC_ + g * 16 + o) * HW_ + pix0 + pix_l] = acc[o];

    // norm: per-group partial (o ascending), then 4 partials g-ascending
    float p = 0.0f;
    #pragma unroll
    for (int o = 0; o < 16; ++o) p = fmaf(acc[o], acc[o], p);
    nrmp[pix_l][g] = p;
    __syncthreads();

    if (t < 64) {
        float nrm = ((nrmp[t][0] + nrmp[t][1]) + nrmp[t][2]) + nrmp[t][3];
        norms[b * HW_ + pix0 + t] = nrm;
    }
}

// ---------------------------------------------------------------------------
// k3 v2 (unchanged, passed R3/R4): radix-select exact 256th-largest key,
// compact >= T, bitonic-sort 512 -> exact jax.lax.top_k order.
// Also writes the full sw plane.
// ---------------------------------------------------------------------------
__global__ __launch_bounds__(512) void k_topk(
        const float* __restrict__ norms, unsigned int* __restrict__ topk,
        float* __restrict__ sw_out) {
    __shared__ unsigned int keys[HW_];               // 12.25 KB
    __shared__ unsigned int hist[256];
    __shared__ unsigned long long sortbuf[512];      // 4 KB
    __shared__ unsigned int s_prefix, s_need, s_cnt;
    __shared__ unsigned char flags[HW_];

    int b = blockIdx.x;
    int t = threadIdx.x;
    const float* nb = norms + b * HW_;

    for (int i = t; i < HW_; i += 512) {
        keys[i] = __float_as_uint(nb[i]);
        flags[i] = 0;
    }
    if (t == 0) { s_prefix = 0u; s_need = K_; s_cnt = 0u; }
    for (int i = t; i < 512; i += 512) sortbuf[i] = ~0ULL;

    for (int r = 0; r < 4; ++r) {
        if (t < 256) hist[t] = 0u;
        __syncthreads();
        unsigned int pfx = s_prefix;
        int shift = 24 - 8 * r;
        for (int i = t; i < HW_; i += 512) {
            unsigned int k = keys[i];
            bool ok = (r == 0) || ((k >> (32 - 8 * r)) == pfx);
            if (ok) atomicAdd(&hist[(k >> shift) & 0xFFu], 1u);
        }
        __syncthreads();
        if (t < 64) {                                // wave 0: suffix-scan
            unsigned int h0 = hist[4 * t + 0];
            unsigned int h1 = hist[4 * t + 1];
            unsigned int h2 = hist[4 * t + 2];
            unsigned int h3 = hist[4 * t + 3];
            unsigned int tot = h0 + h1 + h2 + h3;
            unsigned int suf = tot;
            #pragma unroll
            for (int off = 1; off < 64; off <<= 1) {
                unsigned int v = __shfl_down(suf, off);
                suf += (t + off < 64) ? v : 0u;
            }
            unsigned int g0 = suf;
            unsigned int g1 = suf - h0;
            unsigned int g2 = g1 - h1;
            unsigned int g3 = g2 - h2;
            unsigned int g4 = g3 - h3;
            unsigned int need = s_need;
            if (g0 >= need && g1 < need) { s_prefix = (pfx << 8) | (4u*t+0u); s_need = need - g1; }
            if (g1 >= need && g2 < need) { s_prefix = (pfx << 8) | (4u*t+1u); s_need = need - g2; }
            if (g2 >= need && g3 < need) { s_prefix = (pfx << 8) | (4u*t+2u); s_need = need - g3; }
            if (g3 >= need && g4 < need) { s_prefix = (pfx << 8) | (4u*t+3u); s_need = need - g4; }
        }
        __syncthreads();
    }
    unsigned int T = s_prefix;

    for (int i = t; i < HW_; i += 512) {
        unsigned int k = keys[i];
        if (k >= T) {
            unsigned int pos = atomicAdd(&s_cnt, 1u);
            if (pos < 512)
                sortbuf[pos] = ((unsigned long long)(~k) << 32) | (unsigned int)i;
        }
    }
    __syncthreads();

    for (int kk = 2; kk <= 512; kk <<= 1) {
        for (int j = kk >> 1; j > 0; j >>= 1) {
            int ixj = t ^ j;
            if (ixj > t) {
                unsigned long long a = sortbuf[t], c = sortbuf[ixj];
                bool up = ((t & kk) == 0);
                if ((a > c) == up) { sortbuf[t] = c; sortbuf[ixj] = a; }
            }
            __syncthreads();
        }
    }

    if (t < K_) {
        unsigned long long e = sortbuf[t];
        unsigned int idx = (unsigned int)(e & 0xFFFFFFFFu);
        topk[b * K_ + t] = idx;
        flags[idx] = 1;
    }
    __syncthreads();

    float* swb = sw_out + b * HW_;
    for (int i = t; i < HW_; i += 512)
        swb[i] = flags[i] ? 1.0f : 0.0f;
}

// ---------------------------------------------------------------------------
// k4 v2 (unchanged): pure gather. One wave per (b,k): lane o reads
// feats[b][o][p], writes the 67-float points row.
// ---------------------------------------------------------------------------
__global__ __launch_bounds__(64) void k_points(
        const float* __restrict__ feats, const unsigned int* __restrict__ topk,
        float* __restrict__ points) {
    int bk = blockIdx.x;                             // 0 .. B*K-1
    int b = bk >> 8;                                 // K = 256
    int o = threadIdx.x;
    unsigned int p = topk[bk];

    float v = feats[(size_t)(b * C_ENC_ + o) * HW_ + p];
    float* row = points + (size_t)bk * PTS_ROW_;
    row[3 + o] = v;
    if (o == 0) {
        row[0] = (float)(p % W_);                    // abs_ (x)
        row[1] = (float)(p / W_);                    // ord_ (y)
        row[2] = 0.0f;                               // depth
    }
}

// ---------------------------------------------------------------------------
// k5 v2 (unchanged): x_out[b][o] = mean over K of feats[b][o][idx_k],
// k ascending (reference order). Indices staged in LDS.
// ---------------------------------------------------------------------------
__global__ __launch_bounds__(64) void k_xout(
        const float* __restrict__ feats, const unsigned int* __restrict__ topk,
        float* __restrict__ xout) {
    __shared__ unsigned int sidx[K_];
    int b = blockIdx.x;
    int t = threadIdx.x;
    for (int r = t; r < K_; r += 64) sidx[r] = topk[b * K_ + r];
    __syncthreads();

    const float* fb = feats + (size_t)(b * C_ENC_ + t) * HW_;
    float s = 0.0f;
    #pragma unroll 8
    for (int k = 0; k < K_; ++k) s += fb[sidx[k]];
    xout[b * C_ENC_ + t] = s * (1.0f / K_);
}

// ---------------------------------------------------------------------------
extern "C" void kernel_launch(void* const* d_in, const int* in_sizes, int n_in,
                              void* d_out, int out_size, void* d_ws, size_t ws_size,
                              hipStream_t stream) {
    const float* F    = (const float*)d_in[0];       // [B, C_IN, H, W]
    const float* w    = (const float*)d_in[1];       // [C_ENC, C_IN]
    const float* bias = (const float*)d_in[2];       // [C_ENC]

    float* out    = (float*)d_out;
    float* xout   = out;                             // [B, C_ENC]      (2048)
    float* sw     = out + B_ * C_ENC_;               // [B, 1, H, W]    (100352)
    float* points = sw + BHW_;                       // [B, K, 67]      (548864)

    // workspace: feats [B,64,HW] 25.7MB | Wt 128KB | norms 392KB | topk 32KB
    float* feats         = (float*)d_ws;
    float* wt            = feats + (size_t)B_ * C_ENC_ * HW_;
    float* norms         = wt + C_IN_ * C_ENC_;
    unsigned int* topk   = (unsigned int*)(norms + BHW_);

    k_transpose_w<<<128, 256, 0, stream>>>(w, wt);
    k_conv_norm  <<<BHW_ / 64, 256, 0, stream>>>(F, wt, bias, norms, feats);
    k_topk       <<<B_, 512, 0, stream>>>(norms, topk, sw);
    k_points     <<<B_ * K_, 64, 0, stream>>>(feats, topk, points);
    k_xout       <<<B_, 64, 0, stream>>>(feats, topk, xout);
}